// Round 5
// baseline (373.528 us; speedup 1.0000x reference)
//
#include <hip/hip_runtime.h>
#include <hip/hip_bf16.h>

typedef unsigned int uint;
typedef unsigned short ushort;
typedef __attribute__((ext_vector_type(8))) short bf16x8;
typedef __attribute__((ext_vector_type(4))) float f32x4;

#define Tn 128
#define Bn 16
#define HH 128
#define G3 384
#define DIN 1024
#define PAD 136   // ushort row stride for 128-wide LDS tiles (byte stride 272 = 16B-aligned, breaks bank conflicts)

__device__ __forceinline__ ushort f2bf(float f){
    union{float f; uint u;} c; c.f = f;
    uint u = c.u + 0x7fffu + ((c.u >> 16) & 1u);   // RNE to bf16
    return (ushort)(u >> 16);
}
__device__ __forceinline__ uint pack2(float a, float b){
    return ((uint)f2bf(b) << 16) | (uint)f2bf(a);
}
__device__ __forceinline__ float sigm(float x){ return 1.f/(1.f + __expf(-x)); }
__device__ __forceinline__ float tanhx(float x){
    float t = __expf(-2.f*fabsf(x));
    float r = (1.f - t)/(1.f + t);
    return x >= 0.f ? r : -r;
}
__device__ __forceinline__ float lo16u(uint u){ union{uint i; float f;} c; c.i = u << 16; return c.f; }
__device__ __forceinline__ float hi16u(uint u){ union{uint i; float f;} c; c.i = u & 0xffff0000u; return c.f; }

// ============ fused emb + Gi + WoE, all MFMA. 16 blocks x 512 threads.
// Phase 1: emb(128x128) = x_stripe(128x1024) @ Wemb^T, emb kept in LDS as bf16.
// Phase 2: Gi = emb @ Wih^T + bih for both GRUs (6 N-chunks of 128 gates),
//          written bf16, P-permuted, [pos][b][g] layout. WoE = Wo[e]*emb bf16.
__global__ __launch_bounds__(512, 1) void k_embgi(
    const float* __restrict__ x,    const float* __restrict__ Wemb,
    const float* __restrict__ Wiha, const float* __restrict__ biha,
    const float* __restrict__ Wihb, const float* __restrict__ bihb,
    const float* __restrict__ Wo,
    ushort* __restrict__ gia, ushort* __restrict__ gib, ushort* __restrict__ woE)
{
    __shared__ __align__(16) ushort LA[128*PAD];  // x chunk; later emb bf16 [m][e]
    __shared__ __align__(16) ushort LB[128*PAD];  // weight chunk [row][k]
    int tid = threadIdx.x;
    int lane = tid & 63, wave = tid >> 6;
    int quad = lane >> 4, n = lane & 15;
    int R0 = blockIdx.x * 128;
    int tr = tid >> 2, cb = (tid & 3) * 32;   // staging: row tr, 32 cols at cb

    f32x4 acc[8];
#pragma unroll
    for (int t = 0; t < 8; ++t) acc[t] = (f32x4){0.f,0.f,0.f,0.f};

    // ---- Phase 1: K-loop over 8 chunks of 128
    for (int kc = 0; kc < 8; ++kc){
        __syncthreads();
        {   // stage x -> LA, Wemb -> LB (fp32 -> bf16)
            const float4* sx = (const float4*)(x    + (size_t)(R0 + tr)*DIN + kc*128 + cb);
            const float4* sw = (const float4*)(Wemb + (size_t)tr*DIN       + kc*128 + cb);
            float4 f0=sx[0],f1=sx[1],f2=sx[2],f3=sx[3],f4=sx[4],f5=sx[5],f6=sx[6],f7=sx[7];
            uint4* dA = (uint4*)&LA[tr*PAD + cb];
            dA[0] = (uint4){pack2(f0.x,f0.y),pack2(f0.z,f0.w),pack2(f1.x,f1.y),pack2(f1.z,f1.w)};
            dA[1] = (uint4){pack2(f2.x,f2.y),pack2(f2.z,f2.w),pack2(f3.x,f3.y),pack2(f3.z,f3.w)};
            dA[2] = (uint4){pack2(f4.x,f4.y),pack2(f4.z,f4.w),pack2(f5.x,f5.y),pack2(f5.z,f5.w)};
            dA[3] = (uint4){pack2(f6.x,f6.y),pack2(f6.z,f6.w),pack2(f7.x,f7.y),pack2(f7.z,f7.w)};
            float4 g0=sw[0],g1=sw[1],g2=sw[2],g3=sw[3],g4=sw[4],g5=sw[5],g6=sw[6],g7=sw[7];
            uint4* dB = (uint4*)&LB[tr*PAD + cb];
            dB[0] = (uint4){pack2(g0.x,g0.y),pack2(g0.z,g0.w),pack2(g1.x,g1.y),pack2(g1.z,g1.w)};
            dB[1] = (uint4){pack2(g2.x,g2.y),pack2(g2.z,g2.w),pack2(g3.x,g3.y),pack2(g3.z,g3.w)};
            dB[2] = (uint4){pack2(g4.x,g4.y),pack2(g4.z,g4.w),pack2(g5.x,g5.y),pack2(g5.z,g5.w)};
            dB[3] = (uint4){pack2(g6.x,g6.y),pack2(g6.z,g6.w),pack2(g7.x,g7.y),pack2(g7.z,g7.w)};
        }
        __syncthreads();
#pragma unroll
        for (int kb = 0; kb < 4; ++kb){
            bf16x8 a = *(const bf16x8*)&LA[(wave*16 + n)*PAD + kb*32 + quad*8];
#pragma unroll
            for (int nt = 0; nt < 8; ++nt){
                bf16x8 b = *(const bf16x8*)&LB[(nt*16 + n)*PAD + kb*32 + quad*8];
                acc[nt] = __builtin_amdgcn_mfma_f32_16x16x32_bf16(a, b, acc[nt], 0,0,0);
            }
        }
    }
    __syncthreads();   // done reading LA/LB
    // ---- Phase 1 epilogue: emb bf16 -> LA[m][e]; WoE -> global
#pragma unroll
    for (int nt = 0; nt < 8; ++nt){
        int e = nt*16 + n;
        float wo = Wo[e];
#pragma unroll
        for (int l = 0; l < 4; ++l){
            int m = wave*16 + quad*4 + l;
            float v = acc[nt][l];
            LA[m*PAD + e] = f2bf(v);
            int row = R0 + m; int b = row >> 7, pos = row & 127;
            woE[((size_t)(pos*Bn + b))*HH + e] = f2bf(wo * v);
        }
    }
    __syncthreads();

    // ---- Phase 2: 6 N-chunks of 128 gate rows (3 for GRU-a, 3 for GRU-b)
    for (int nc = 0; nc < 6; ++nc){
        const float* Wsrc = (nc < 3) ? (Wiha + (size_t)nc*128*HH)
                                     : (Wihb + (size_t)(nc-3)*128*HH);
        {   // stage W chunk -> LB
            const float4* sw = (const float4*)(Wsrc + (size_t)tr*HH + cb);
            float4 g0=sw[0],g1=sw[1],g2=sw[2],g3=sw[3],g4=sw[4],g5=sw[5],g6=sw[6],g7=sw[7];
            uint4* dB = (uint4*)&LB[tr*PAD + cb];
            dB[0] = (uint4){pack2(g0.x,g0.y),pack2(g0.z,g0.w),pack2(g1.x,g1.y),pack2(g1.z,g1.w)};
            dB[1] = (uint4){pack2(g2.x,g2.y),pack2(g2.z,g2.w),pack2(g3.x,g3.y),pack2(g3.z,g3.w)};
            dB[2] = (uint4){pack2(g4.x,g4.y),pack2(g4.z,g4.w),pack2(g5.x,g5.y),pack2(g5.z,g5.w)};
            dB[3] = (uint4){pack2(g6.x,g6.y),pack2(g6.z,g6.w),pack2(g7.x,g7.y),pack2(g7.z,g7.w)};
        }
        __syncthreads();
        f32x4 gacc[8];
#pragma unroll
        for (int t = 0; t < 8; ++t) gacc[t] = (f32x4){0.f,0.f,0.f,0.f};
#pragma unroll
        for (int kb = 0; kb < 4; ++kb){
            bf16x8 a = *(const bf16x8*)&LA[(wave*16 + n)*PAD + kb*32 + quad*8];
#pragma unroll
            for (int nt = 0; nt < 8; ++nt){
                bf16x8 b = *(const bf16x8*)&LB[(nt*16 + n)*PAD + kb*32 + quad*8];
                gacc[nt] = __builtin_amdgcn_mfma_f32_16x16x32_bf16(a, b, gacc[nt], 0,0,0);
            }
        }
        ushort* dst = (nc < 3) ? gia : gib;
        const float* bsrc = (nc < 3) ? biha : bihb;
        int gbase = (nc < 3 ? nc : nc - 3) * 128;
#pragma unroll
        for (int nt = 0; nt < 8; ++nt){
            int g = gbase + nt*16 + n;
            float bias = bsrc[g];
            int gamma = g >> 7, j = g & 127;
            int P = ((3*(j >> 4) + gamma) << 4) + (j & 15);
#pragma unroll
            for (int l = 0; l < 4; ++l){
                int m = wave*16 + quad*4 + l;
                int row = R0 + m; int b = row >> 7, pos = row & 127;
                dst[((size_t)(pos*Bn + b))*G3 + P] = f2bf(gacc[nt][l] + bias);
            }
        }
        __syncthreads();   // before next chunk restages LB
    }
}

// ============ Fused GRU recurrence body, compile-time GT (0=a, 1=b).
// 8 waves, 16 chains (all b); one barrier per step; wave-local gate update.
template<int GT>
__device__ __forceinline__ void gru_body(
    const float* __restrict__ Whh, const float* __restrict__ bhh,
    const float* __restrict__ Wsc, const float* __restrict__ bsc,
    const ushort* __restrict__ Gi, const ushort* __restrict__ WoE,
    float* __restrict__ outW, int i)
{
    constexpr int NT = GT ? 4 : 3;
    __shared__ __align__(16) ushort HF[2][2048];   // h in B-frag order, dbuf
    __shared__ float RED[2][128];                  // per-(wave,chain) partials, dbuf
    int tid = threadIdx.x;
    int lane = tid & 63, u = tid >> 6;
    int quad = lane >> 4, n = lane & 15;
    int jb = u*16 + quad*4;     // 4 h-dims this thread owns (chain n)

    // ---- static A-fragments (row-permuted weights), fully unrolled -> registers
    bf16x8 afr[NT][4];
#pragma unroll
    for (int g = 0; g < NT; ++g){
        const float* src = (g < 3) ? (Whh + (size_t)(g*HH + u*16 + n)*HH)
                                   : (Wsc + (size_t)(u*16 + n)*HH);
#pragma unroll
        for (int kb = 0; kb < 4; ++kb){
            const float* p = src + kb*32 + quad*8;
            float4 a = *(const float4*)p, b2 = *(const float4*)(p+4);
            union { uint4 q; bf16x8 v; } cv;
            cv.q.x = pack2(a.x,a.y);  cv.q.y = pack2(a.z,a.w);
            cv.q.z = pack2(b2.x,b2.y); cv.q.w = pack2(b2.z,b2.w);
            afr[g][kb] = cv.v;
        }
    }
    float bh0[4], bh1[4], bh2[4], wsc4[4];
#pragma unroll
    for (int l = 0; l < 4; ++l){
        bh0[l] = bhh[jb+l]; bh1[l] = bhh[HH+jb+l]; bh2[l] = bhh[2*HH+jb+l];
        wsc4[l] = GT ? bsc[jb+l] : Wsc[jb+l];   // GT1: bb[e]; GT0: Wa[j]
    }
    float bav = GT ? 0.f : bsc[0];
    float h4[4] = {0.f,0.f,0.f,0.f};
    if (tid < 256){ uint4 z = {0,0,0,0}; ((uint4*)HF[1])[tid] = z; }

    const ushort* gbase = Gi + (size_t)(i*Bn + n)*G3 + u*48 + quad*4;
    uint2 pg0 = *(const uint2*)(gbase);
    uint2 pg1 = *(const uint2*)(gbase + 16);
    uint2 pg2 = *(const uint2*)(gbase + 32);
    uint2 pwo = {0,0};
    __syncthreads();

    for (int k = 0; k <= i; ++k){
        int pos = i - k;
        // finish previous step's scalar (pipelined by one step)
        if (tid < 16 && ((GT == 0 && k > 0) || (GT == 1 && k > 1))){
            const float* R = RED[(k+1)&1];
            float sum = R[tid]+R[16+tid]+R[32+tid]+R[48+tid]
                      + R[64+tid]+R[80+tid]+R[96+tid]+R[112+tid];
            int idx = GT ? (k-2) : (k-1);
            outW[((size_t)tid*Tn + i)*Tn + idx] = GT ? sum : (0.5f*sum + bav);
        }
        uint2 g0 = pg0, g1 = pg1, g2 = pg2, wo = pwo;
        int pnext = (pos > 0) ? pos - 1 : 0;
        const ushort* gb2 = Gi + (size_t)(pnext*Bn + n)*G3 + u*48 + quad*4;
        pg0 = *(const uint2*)(gb2);
        pg1 = *(const uint2*)(gb2 + 16);
        pg2 = *(const uint2*)(gb2 + 32);
        if (GT) pwo = *(const uint2*)(WoE + (size_t)(pos*Bn + n)*HH + jb);

        const ushort* HR = HF[(k+1)&1];
        bf16x8 bfr[4];
#pragma unroll
        for (int kb = 0; kb < 4; ++kb)
            bfr[kb] = *(const bf16x8*)&HR[(64*kb + lane)*8];

        f32x4 acc[NT];
#pragma unroll
        for (int g = 0; g < NT; ++g){
            f32x4 a_ = {0.f,0.f,0.f,0.f};
#pragma unroll
            for (int kb = 0; kb < 4; ++kb)
                a_ = __builtin_amdgcn_mfma_f32_16x16x32_bf16(afr[g][kb], bfr[kb], a_, 0,0,0);
            acc[g] = a_;
        }

        float part = 0.f;
        if (GT){   // q_{k-1}: Pb(h_{k-1}) with WoE[pos_{k-1}] (prefetched last step)
            float wof[4] = {lo16u(wo.x), hi16u(wo.x), lo16u(wo.y), hi16u(wo.y)};
#pragma unroll
            for (int l = 0; l < 4; ++l){
                float beta = tanhx(0.5f*acc[NT-1][l] + wsc4[l]);
                part = fmaf(wof[l], beta, part);
            }
        }
        float gi0[4] = {lo16u(g0.x), hi16u(g0.x), lo16u(g0.y), hi16u(g0.y)};
        float gi1[4] = {lo16u(g1.x), hi16u(g1.x), lo16u(g1.y), hi16u(g1.y)};
        float gi2[4] = {lo16u(g2.x), hi16u(g2.x), lo16u(g2.y), hi16u(g2.y)};
#pragma unroll
        for (int l = 0; l < 4; ++l){
            float r = sigm(gi0[l] + acc[0][l] + bh0[l]);
            float z = sigm(gi1[l] + acc[1][l] + bh1[l]);
            float nn = tanhx(gi2[l] + r*(acc[2][l] + bh2[l]));
            h4[l] = (1.f - z)*nn + z*h4[l];
        }
        if (!GT) part = wsc4[0]*h4[0] + wsc4[1]*h4[1] + wsc4[2]*h4[2] + wsc4[3]*h4[3];

        {
            ushort* HW = HF[k&1];
            uint2 hw = { pack2(h4[0], h4[1]), pack2(h4[2], h4[3]) };
            *(uint2*)&HW[((jb>>3)*16 + n)*8 + (jb&4)] = hw;
        }
        part += __shfl_xor(part, 16);
        part += __shfl_xor(part, 32);
        if (lane < 16) RED[k&1][u*16 + n] = part;
        __syncthreads();
    }

    // ---- tail
    if (tid < 16){
        const float* R = RED[i&1];
        float sum = R[tid]+R[16+tid]+R[32+tid]+R[48+tid]
                  + R[64+tid]+R[80+tid]+R[96+tid]+R[112+tid];
        if (GT == 0)      outW[((size_t)tid*Tn + i)*Tn + i] = 0.5f*sum + bav;
        else if (i > 0)   outW[((size_t)tid*Tn + i)*Tn + (i-1)] = sum;
    }
    if (GT){   // q_i: Pb(h_i) with WoE[0] (in pwo)
        const ushort* HR = HF[i&1];
        bf16x8 bfr[4];
#pragma unroll
        for (int kb = 0; kb < 4; ++kb)
            bfr[kb] = *(const bf16x8*)&HR[(64*kb + lane)*8];
        f32x4 a_ = {0.f,0.f,0.f,0.f};
#pragma unroll
        for (int kb = 0; kb < 4; ++kb)
            a_ = __builtin_amdgcn_mfma_f32_16x16x32_bf16(afr[NT-1][kb], bfr[kb], a_, 0,0,0);
        float wof[4] = {lo16u(pwo.x), hi16u(pwo.x), lo16u(pwo.y), hi16u(pwo.y)};
        float part = 0.f;
#pragma unroll
        for (int l = 0; l < 4; ++l){
            float beta = tanhx(0.5f*a_[l] + wsc4[l]);
            part = fmaf(wof[l], beta, part);
        }
        part += __shfl_xor(part, 16);
        part += __shfl_xor(part, 32);
        if (lane < 16) RED[(i+1)&1][u*16 + n] = part;
        __syncthreads();
        if (tid < 16){
            const float* R = RED[(i+1)&1];
            float sum = R[tid]+R[16+tid]+R[32+tid]+R[48+tid]
                      + R[64+tid]+R[80+tid]+R[96+tid]+R[112+tid];
            outW[((size_t)tid*Tn + i)*Tn + i] = sum;
        }
    }
}

// grid = 256 linear; gtype = blk & 1 so each XCD (id%8) hosts only one GRU type
// -> per-XCD L2 working set ~2 MB (bf16 Gi), everything L2-resident.
__global__ __launch_bounds__(512, 2) void k_gru(
    const float* __restrict__ WhhA, const float* __restrict__ bhhA,
    const float* __restrict__ Wa,   const float* __restrict__ ba,
    const float* __restrict__ WhhB, const float* __restrict__ bhhB,
    const float* __restrict__ Wb,   const float* __restrict__ bb,
    const ushort* __restrict__ GiA, const ushort* __restrict__ GiB,
    const ushort* __restrict__ WoE,
    float* __restrict__ sW, float* __restrict__ qW)
{
    int i = Tn - 1 - (blockIdx.x >> 1);
    if ((blockIdx.x & 1) == 0) gru_body<0>(WhhA, bhhA, Wa, ba, GiA, nullptr, sW, i);
    else                       gru_body<1>(WhhB, bhhB, Wb, bb, GiB, WoE,    qW, i);
}

// ============ softmax(s) . q per row; one wave per (b,i)
__global__ __launch_bounds__(256) void k_out(const float* __restrict__ sW,
                                             const float* __restrict__ qW,
                                             const float* __restrict__ bo,
                                             float* __restrict__ out){
    int tid = threadIdx.x, lane = tid & 63, w = tid >> 6;
    int r = blockIdx.x*4 + w;
    int i = r & (Tn-1);
    const float* s = sW + (size_t)r*Tn;
    const float* q = qW + (size_t)r*Tn;
    float s0 = (lane     <= i) ? s[lane]      : -1e30f;
    float s1 = (64+lane  <= i) ? s[64+lane]   : -1e30f;
    float m = fmaxf(s0, s1);
#pragma unroll
    for (int off = 32; off; off >>= 1) m = fmaxf(m, __shfl_xor(m, off));
    float e0 = __expf(s0 - m), e1 = __expf(s1 - m);
    float q0 = (lane    <= i) ? q[lane]    : 0.f;
    float q1 = (64+lane <= i) ? q[64+lane] : 0.f;
    float num = e0*q0 + e1*q1, den = e0 + e1;
#pragma unroll
    for (int off = 32; off; off >>= 1){
        num += __shfl_xor(num, off);
        den += __shfl_xor(den, off);
    }
    if (lane == 0) out[r] = num/den + bo[0];
}

extern "C" void kernel_launch(void* const* d_in, const int* in_sizes, int n_in,
                              void* d_out, int out_size, void* d_ws, size_t ws_size,
                              hipStream_t stream) {
    const float* x     = (const float*)d_in[0];
    const float* Wemb  = (const float*)d_in[1];
    const float* Wih_a = (const float*)d_in[2];
    const float* Whh_a = (const float*)d_in[3];
    const float* bih_a = (const float*)d_in[4];
    const float* bhh_a = (const float*)d_in[5];
    const float* Wa    = (const float*)d_in[6];
    const float* ba    = (const float*)d_in[7];
    const float* Wih_b = (const float*)d_in[8];
    const float* Whh_b = (const float*)d_in[9];
    const float* bih_b = (const float*)d_in[10];
    const float* bhh_b = (const float*)d_in[11];
    const float* Wb    = (const float*)d_in[12];
    const float* bb    = (const float*)d_in[13];
    const float* Wo    = (const float*)d_in[14];
    const float* bo    = (const float*)d_in[15];

    const int NR = Bn*Tn;                            // 2048 rows
    ushort* giA = (ushort*)d_ws;                     // [pos][b][384] bf16, P-permuted
    ushort* giB = giA + (size_t)NR*G3;
    ushort* woE = giB + (size_t)NR*G3;               // [pos][b][128] bf16
    float*  sW  = (float*)(woE + (size_t)NR*HH);     // [b][i][k] fp32
    float*  qW  = sW + (size_t)NR*Tn;

    k_embgi<<<dim3(16), 512, 0, stream>>>(x, Wemb, Wih_a, bih_a, Wih_b, bih_b, Wo,
                                          giA, giB, woE);
    k_gru<<<dim3(256), 512, 0, stream>>>(Whh_a, bhh_a, Wa, ba,
                                         Whh_b, bhh_b, Wb, bb,
                                         giA, giB, woE, sW, qW);
    k_out<<<dim3(NR/4), 256, 0, stream>>>(sW, qW, bo, (float*)d_out);
}